// Round 7
// baseline (412.932 us; speedup 1.0000x reference)
//
#include <hip/hip_runtime.h>
#include <hip/hip_fp16.h>

#define DD 128
#define GG 256
#define RANGES 8
#define RSMAX 6400
#define NCHUNK 32

typedef _Float16 half8 __attribute__((ext_vector_type(8)));
typedef float floatx4 __attribute__((ext_vector_type(4)));

__device__ inline uint2 pack_half4(float4 v) {
    __half2 a = __floats2half2_rn(v.x, v.y);
    __half2 b = __floats2half2_rn(v.z, v.w);
    uint2 u;
    u.x = *reinterpret_cast<unsigned int*>(&a);
    u.y = *reinterpret_cast<unsigned int*>(&b);
    return u;
}

// ---------------- LDS range-partitioned histogram ----------------
__global__ __launch_bounds__(256) void k_hist2(const int* __restrict__ src, const int* __restrict__ dst,
                                               int* __restrict__ pout, int* __restrict__ pin,
                                               int E, int N, int C, int RS, int L) {
    __shared__ int ho[RSMAX];
    __shared__ int hi[RSMAX];
    int r = blockIdx.x / C;
    int c = blockIdx.x % C;
    int r0 = r * RS;
    int r1 = min(r0 + RS, N);
    int nb = r1 - r0;
    for (int i = threadIdx.x; i < nb; i += 256) { ho[i] = 0; hi[i] = 0; }
    __syncthreads();
    int e0 = c * L, e1 = min(e0 + L, E);
    for (int e = e0 + threadIdx.x * 4; e < e1; e += 1024) {
        if (e + 3 < e1) {
            int4 s4 = *(const int4*)&src[e];
            int4 d4 = *(const int4*)&dst[e];
            if (s4.x >= r0 && s4.x < r1) atomicAdd(&ho[s4.x - r0], 1);
            if (s4.y >= r0 && s4.y < r1) atomicAdd(&ho[s4.y - r0], 1);
            if (s4.z >= r0 && s4.z < r1) atomicAdd(&ho[s4.z - r0], 1);
            if (s4.w >= r0 && s4.w < r1) atomicAdd(&ho[s4.w - r0], 1);
            if (d4.x >= r0 && d4.x < r1) atomicAdd(&hi[d4.x - r0], 1);
            if (d4.y >= r0 && d4.y < r1) atomicAdd(&hi[d4.y - r0], 1);
            if (d4.z >= r0 && d4.z < r1) atomicAdd(&hi[d4.z - r0], 1);
            if (d4.w >= r0 && d4.w < r1) atomicAdd(&hi[d4.w - r0], 1);
        } else {
            for (int j = 0; j < 4 && e + j < e1; ++j) {
                int s = src[e + j], d = dst[e + j];
                if (s >= r0 && s < r1) atomicAdd(&ho[s - r0], 1);
                if (d >= r0 && d < r1) atomicAdd(&hi[d - r0], 1);
            }
        }
    }
    __syncthreads();
    for (int i = threadIdx.x; i < nb; i += 256) {
        pout[(size_t)c * N + r0 + i] = ho[i];
        pin[(size_t)c * N + r0 + i] = hi[i];
    }
}

__global__ void k_reduce(const int* __restrict__ pout, const int* __restrict__ pin,
                         float* __restrict__ norm_out, float* __restrict__ norm_in,
                         int* __restrict__ deg_in, int N, int C) {
    int n = blockIdx.x * blockDim.x + threadIdx.x;
    if (n >= N) return;
    int so = 0, si = 0;
    for (int c = 0; c < C; ++c) {
        so += pout[(size_t)c * N + n];
        si += pin[(size_t)c * N + n];
    }
    norm_out[n] = rsqrtf(fmaxf((float)so, 1.0f));
    norm_in[n] = rsqrtf(fmaxf((float)si, 1.0f));
    deg_in[n] = si;
}

__global__ void k_base(const int* __restrict__ pin, const int* __restrict__ row_ptr,
                       int* __restrict__ base, int N, int C) {
    int n = blockIdx.x * blockDim.x + threadIdx.x;
    if (n >= N) return;
    int run = row_ptr[n];
    for (int c = 0; c < C; ++c) {
        int h = pin[(size_t)c * N + n];
        base[(size_t)c * N + n] = run;
        run += h;
    }
}

__global__ void k_gstart(const int* __restrict__ gid, int* g_start, int N, int G) {
    int g = blockIdx.x * blockDim.x + threadIdx.x;
    if (g > G) return;
    int lo = 0, hi = N;
    while (lo < hi) {
        int mid = (lo + hi) >> 1;
        if (gid[mid] < g) lo = mid + 1; else hi = mid;
    }
    g_start[g] = lo;
}

// ---------------- 3-phase scan ----------------
__global__ __launch_bounds__(256) void k_scan_a(const int* __restrict__ deg, int* bsum, int n) {
    __shared__ int wsum[4];
    int base = blockIdx.x * 1024 + threadIdx.x * 4;
    int s = 0;
    #pragma unroll
    for (int j = 0; j < 4; ++j) s += (base + j < n) ? deg[base + j] : 0;
    #pragma unroll
    for (int off = 32; off; off >>= 1) s += __shfl_xor(s, off);
    int lane = threadIdx.x & 63, w = threadIdx.x >> 6;
    if (lane == 0) wsum[w] = s;
    __syncthreads();
    if (threadIdx.x == 0) bsum[blockIdx.x] = wsum[0] + wsum[1] + wsum[2] + wsum[3];
}

__global__ void k_scan_b(int* bsum, int nblk, int* row_ptr, int n) {
    int lane = threadIdx.x;
    int carry = 0;
    for (int base = 0; base < nblk; base += 64) {
        int i = base + lane;
        int v = (i < nblk) ? bsum[i] : 0;
        int s = v;
        #pragma unroll
        for (int off = 1; off < 64; off <<= 1) {
            int u = __shfl_up(s, off);
            if (lane >= off) s += u;
        }
        if (i < nblk) bsum[i] = carry + s - v;
        carry += __shfl(s, 63);
    }
    if (lane == 0) row_ptr[n] = carry;
}

__global__ __launch_bounds__(256) void k_scan_c(const int* __restrict__ deg, const int* __restrict__ bsum,
                                                int* row_ptr, int n) {
    __shared__ int wsum[4];
    int t = threadIdx.x;
    int base = blockIdx.x * 1024 + t * 4;
    int v[4];
    #pragma unroll
    for (int j = 0; j < 4; ++j) v[j] = (base + j < n) ? deg[base + j] : 0;
    int ts = v[0] + v[1] + v[2] + v[3];
    int lane = t & 63, w = t >> 6;
    int incl = ts;
    #pragma unroll
    for (int off = 1; off < 64; off <<= 1) {
        int u = __shfl_up(incl, off);
        if (lane >= off) incl += u;
    }
    if (lane == 63) wsum[w] = incl;
    __syncthreads();
    int woff = 0;
    for (int j = 0; j < w; ++j) woff += wsum[j];
    int run = bsum[blockIdx.x] + woff + incl - ts;
    #pragma unroll
    for (int j = 0; j < 4; ++j) {
        if (base + j < n) row_ptr[base + j] = run;
        run += v[j];
    }
}

// fill CSR: LDS slot counters seeded from per-chunk base (no per-edge base reads)
__global__ __launch_bounds__(256) void k_fill2(const int* __restrict__ src, const int* __restrict__ dst,
                                               const int* __restrict__ base, int* __restrict__ col_src,
                                               int E, int N, int C, int RS, int L) {
    __shared__ int cnt[RSMAX];
    int r = blockIdx.x / C;
    int c = blockIdx.x % C;
    int r0 = r * RS;
    int r1 = min(r0 + RS, N);
    int nb = r1 - r0;
    const int* bc = base + (size_t)c * N;
    for (int i = threadIdx.x; i < nb; i += 256) cnt[i] = bc[r0 + i];
    __syncthreads();
    int e0 = c * L, e1 = min(e0 + L, E);
    for (int e = e0 + threadIdx.x * 4; e < e1; e += 1024) {
        if (e + 3 < e1) {
            int4 s4 = *(const int4*)&src[e];
            int4 d4 = *(const int4*)&dst[e];
            if (d4.x >= r0 && d4.x < r1) { int o = atomicAdd(&cnt[d4.x - r0], 1); col_src[o] = s4.x; }
            if (d4.y >= r0 && d4.y < r1) { int o = atomicAdd(&cnt[d4.y - r0], 1); col_src[o] = s4.y; }
            if (d4.z >= r0 && d4.z < r1) { int o = atomicAdd(&cnt[d4.z - r0], 1); col_src[o] = s4.z; }
            if (d4.w >= r0 && d4.w < r1) { int o = atomicAdd(&cnt[d4.w - r0], 1); col_src[o] = s4.w; }
        } else {
            for (int j = 0; j < 4 && e + j < e1; ++j) {
                int s = src[e + j], d = dst[e + j];
                if (d >= r0 && d < r1) { int o = atomicAdd(&cnt[d - r0], 1); col_src[o] = s; }
            }
        }
    }
}

// W[l] f32 [k][n] -> Wt half [n][k]
__global__ void k_wconv(const float* __restrict__ W, __half* __restrict__ Wt) {
    int i = blockIdx.x * blockDim.x + threadIdx.x;  // 3*16384
    if (i >= 3 * 16384) return;
    int l = i >> 14;
    int rem = i & 16383;
    int n = rem >> 7;
    int k = rem & 127;
    Wt[(size_t)l * 16384 + n * 128 + k] = __float2half(W[(size_t)l * 16384 + k * 128 + n]);
}

// pre-scale rows to half: Xh[n] = half(feats[n] * norm_out[n])
__global__ void k_scale(const float* __restrict__ h, const float* __restrict__ norm_out,
                        uint2* __restrict__ Xh, int N) {
    int i = blockIdx.x * blockDim.x + threadIdx.x;
    if (i < N * 32) {
        int n = i >> 5;
        float4 v = ((const float4*)h)[i];
        float s = norm_out[n];
        v.x *= s; v.y *= s; v.z *= s; v.w *= s;
        Xh[i] = pack_half4(v);
    }
}

__device__ inline void acc_row(float* acc, uint4 u) {
    const __half2* h = (const __half2*)&u;
    #pragma unroll
    for (int i = 0; i < 4; ++i) {
        float2 f = __half22float2(h[i]);
        acc[2 * i] += f.x;
        acc[2 * i + 1] += f.y;
    }
}

// Fused layer: gather-agg (16 lanes/node, uint4 loads, f32 acc) -> LDS half tile -> MFMA GEMM
// -> epilogue relu(.+b) [*norm_out -> half Xout | f32 Fout].
__global__ __launch_bounds__(256) void k_layer(const uint4* __restrict__ Xin, const float* __restrict__ norm_in,
                                               const int* __restrict__ row_ptr, const int* __restrict__ col_src,
                                               const __half* __restrict__ Wt, const float* __restrict__ bl,
                                               const float* __restrict__ scale, float* __restrict__ outf,
                                               __half* __restrict__ outh, int N) {
    __shared__ _Float16 Ah[64 * 136];   // stride 136: 2-way LDS aliasing only (free)
    __shared__ _Float16 Bt[128 * 136];
    int tid = threadIdx.x;
    int n0 = blockIdx.x * 64;

    // stage B^T: 128 rows x 128 halves
    for (int q = tid; q < 2048; q += 256) {
        int r = q >> 4, c = q & 15;
        *(float4*)&Bt[r * 136 + c * 8] = *(const float4*)&Wt[(size_t)r * 128 + c * 8];
    }

    // gather phase: 16 lanes/node, 16 nodes per pass, 4 passes
    int g = tid >> 4;     // node within pass
    int l16 = tid & 15;   // uint4 lane within row
    #pragma unroll
    for (int pass = 0; pass < 4; ++pass) {
        int r = pass * 16 + g;
        int node = n0 + r;
        float acc[8] = {};
        if (node < N) {
            int beg = row_ptr[node], end = row_ptr[node + 1];
            int k = beg;
            for (; k + 1 < end; k += 2) {
                int s0 = col_src[k];
                int s1 = col_src[k + 1];
                uint4 u0 = Xin[(size_t)s0 * 16 + l16];
                uint4 u1 = Xin[(size_t)s1 * 16 + l16];
                acc_row(acc, u0);
                acc_row(acc, u1);
            }
            if (k < end) {
                uint4 u = Xin[(size_t)col_src[k] * 16 + l16];
                acc_row(acc, u);
            }
            float ni = norm_in[node];
            #pragma unroll
            for (int i = 0; i < 8; ++i) acc[i] *= ni;
        }
        __half2 hp[4];
        #pragma unroll
        for (int i = 0; i < 4; ++i) hp[i] = __floats2half2_rn(acc[2 * i], acc[2 * i + 1]);
        *(uint4*)&Ah[r * 136 + l16 * 8] = *(uint4*)hp;
    }
    __syncthreads();

    // MFMA phase
    int wave = tid >> 6;
    int lane = tid & 63;
    int quad = lane >> 4;
    int mrow = lane & 15;
    int m0 = wave * 16;

    half8 af[4];
    #pragma unroll
    for (int kc = 0; kc < 4; ++kc)
        af[kc] = *(const half8*)&Ah[(m0 + mrow) * 136 + kc * 32 + quad * 8];

    floatx4 acc[8];
    #pragma unroll
    for (int ct = 0; ct < 8; ++ct) acc[ct] = (floatx4){0.f, 0.f, 0.f, 0.f};

    #pragma unroll
    for (int ct = 0; ct < 8; ++ct) {
        #pragma unroll
        for (int kc = 0; kc < 4; ++kc) {
            half8 bf = *(const half8*)&Bt[(ct * 16 + mrow) * 136 + kc * 32 + quad * 8];
            acc[ct] = __builtin_amdgcn_mfma_f32_16x16x32_f16(af[kc], bf, acc[ct], 0, 0, 0);
        }
    }

    // epilogue
    float sc[4];
    #pragma unroll
    for (int r = 0; r < 4; ++r) {
        int node = n0 + m0 + quad * 4 + r;
        sc[r] = (scale && node < N) ? scale[node] : 1.0f;
    }
    #pragma unroll
    for (int ct = 0; ct < 8; ++ct) {
        int col = ct * 16 + mrow;
        float bias = bl[col];
        #pragma unroll
        for (int r = 0; r < 4; ++r) {
            int node = n0 + m0 + quad * 4 + r;
            if (node < N) {
                float val = fmaxf(acc[ct][r] + bias, 0.f);
                if (outh) outh[(size_t)node * 128 + col] = __float2half(val * sc[r]);
                else outf[(size_t)node * 128 + col] = val;
            }
        }
    }
}

// pooled mean readout
__global__ __launch_bounds__(128) void k_pool(const float* __restrict__ h, const int* __restrict__ g_start,
                                              float* __restrict__ out) {
    int g = blockIdx.x;
    int t = threadIdx.x;
    int beg = g_start[g], end = g_start[g + 1];
    float acc = 0.0f;
    int n = beg;
    for (; n + 3 < end; n += 4) {
        float a0 = h[(size_t)n * DD + t];
        float a1 = h[(size_t)(n + 1) * DD + t];
        float a2 = h[(size_t)(n + 2) * DD + t];
        float a3 = h[(size_t)(n + 3) * DD + t];
        acc += a0 + a1 + a2 + a3;
    }
    for (; n < end; ++n) acc += h[(size_t)n * DD + t];
    float cnt = (float)(end - beg);
    out[(size_t)g * DD + t] = acc / fmaxf(cnt, 1.0f);
}

extern "C" void kernel_launch(void* const* d_in, const int* in_sizes, int n_in,
                              void* d_out, int out_size, void* d_ws, size_t ws_size,
                              hipStream_t stream) {
    const float* feats = (const float*)d_in[0];
    const float* W = (const float*)d_in[1];
    const float* b = (const float*)d_in[2];
    const int* src = (const int*)d_in[3];
    const int* dst = (const int*)d_in[4];
    const int* gid = (const int*)d_in[5];
    float* out = (float*)d_out;
    const int N = in_sizes[0] / DD;  // 50000
    const int E = in_sizes[3];       // 800000

    const int C = NCHUNK;
    const int RS = (N + RANGES - 1) / RANGES;
    const int L = (((E + C - 1) / C) + 3) & ~3;

    char* ws = (char*)d_ws;
    size_t off = 0;
    auto take = [&](size_t bytes) {
        char* p = ws + off;
        off = (off + bytes + 255) & ~(size_t)255;
        return p;
    };
    float* norm_out = (float*)take((size_t)N * 4);
    float* norm_in  = (float*)take((size_t)N * 4);
    int*   deg_in   = (int*)take((size_t)N * 4);
    int*   row_ptr  = (int*)take((size_t)(N + 1) * 4);
    int*   col_src  = (int*)take((size_t)E * 4);
    int*   g_start  = (int*)take((size_t)(GG + 1) * 4);
    int*   bsum     = (int*)take((size_t)1024 * 4);
    __half* Wth     = (__half*)take((size_t)3 * 16384 * 2);
    uint2* Xa       = (uint2*)take((size_t)N * DD * 2);   // half features ping
    uint2* Xb       = (uint2*)take((size_t)N * DD * 2);   // half features pong
    // union region: preprocessing partials then final-layer F
    size_t part_bytes = 3 * ((size_t)C * N * 4 + 256);
    size_t f_bytes = (size_t)N * DD * 4;
    char* uni = take(part_bytes > f_bytes ? part_bytes : f_bytes);
    int* pout  = (int*)uni;
    int* pin   = (int*)(uni + (((size_t)C * N * 4 + 255) & ~(size_t)255));
    int* fbase = (int*)(uni + 2 * (((size_t)C * N * 4 + 255) & ~(size_t)255));
    float* F   = (float*)uni;  // alias: used only after preprocessing completes

    const int nblk = (N + 1023) / 1024;

    k_hist2<<<RANGES * C, 256, 0, stream>>>(src, dst, pout, pin, E, N, C, RS, L);
    k_reduce<<<(N + 255) / 256, 256, 0, stream>>>(pout, pin, norm_out, norm_in, deg_in, N, C);
    k_gstart<<<1, 512, 0, stream>>>(gid, g_start, N, GG);
    k_wconv<<<(3 * 16384 + 255) / 256, 256, 0, stream>>>(W, Wth);
    k_scan_a<<<nblk, 256, 0, stream>>>(deg_in, bsum, N);
    k_scan_b<<<1, 64, 0, stream>>>(bsum, nblk, row_ptr, N);
    k_scan_c<<<nblk, 256, 0, stream>>>(deg_in, bsum, row_ptr, N);
    k_base<<<(N + 255) / 256, 256, 0, stream>>>(pin, row_ptr, fbase, N, C);
    k_fill2<<<RANGES * C, 256, 0, stream>>>(src, dst, fbase, col_src, E, N, C, RS, L);

    k_scale<<<(N * 32 + 255) / 256, 256, 0, stream>>>(feats, norm_out, Xa, N);

    const int lgrid = (N + 63) / 64;
    // layer 0: Xa -> Xb (half)
    k_layer<<<lgrid, 256, 0, stream>>>((const uint4*)Xa, norm_in, row_ptr, col_src,
                                       Wth, b, norm_out, nullptr, (__half*)Xb, N);
    // layer 1: Xb -> Xa (half)
    k_layer<<<lgrid, 256, 0, stream>>>((const uint4*)Xb, norm_in, row_ptr, col_src,
                                       Wth + 16384, b + DD, norm_out, nullptr, (__half*)Xa, N);
    // layer 2: Xa -> F (f32)
    k_layer<<<lgrid, 256, 0, stream>>>((const uint4*)Xa, norm_in, row_ptr, col_src,
                                       Wth + 32768, b + 2 * DD, nullptr, F, nullptr, N);

    k_pool<<<GG, 128, 0, stream>>>(F, g_start, out);
}

// Round 8
// 320.149 us; speedup vs baseline: 1.2898x; 1.2898x over previous
//
#include <hip/hip_runtime.h>
#include <hip/hip_fp16.h>

#define DD 128
#define GG 256
#define RANGES 8
#define RSMAX 6400
#define NCHUNK 32

typedef _Float16 half8 __attribute__((ext_vector_type(8)));
typedef float floatx4 __attribute__((ext_vector_type(4)));

__device__ inline uint2 pack_half4(float4 v) {
    __half2 a = __floats2half2_rn(v.x, v.y);
    __half2 b = __floats2half2_rn(v.z, v.w);
    uint2 u;
    u.x = *reinterpret_cast<unsigned int*>(&a);
    u.y = *reinterpret_cast<unsigned int*>(&b);
    return u;
}

// ---------------- LDS range-partitioned histogram ----------------
__global__ __launch_bounds__(256) void k_hist2(const int* __restrict__ src, const int* __restrict__ dst,
                                               int* __restrict__ pout, int* __restrict__ pin,
                                               int E, int N, int C, int RS, int L) {
    __shared__ int ho[RSMAX];
    __shared__ int hi[RSMAX];
    int r = blockIdx.x / C;
    int c = blockIdx.x % C;
    int r0 = r * RS;
    int r1 = min(r0 + RS, N);
    int nb = r1 - r0;
    for (int i = threadIdx.x; i < nb; i += 256) { ho[i] = 0; hi[i] = 0; }
    __syncthreads();
    int e0 = c * L, e1 = min(e0 + L, E);
    for (int e = e0 + threadIdx.x * 4; e < e1; e += 1024) {
        if (e + 3 < e1) {
            int4 s4 = *(const int4*)&src[e];
            int4 d4 = *(const int4*)&dst[e];
            if (s4.x >= r0 && s4.x < r1) atomicAdd(&ho[s4.x - r0], 1);
            if (s4.y >= r0 && s4.y < r1) atomicAdd(&ho[s4.y - r0], 1);
            if (s4.z >= r0 && s4.z < r1) atomicAdd(&ho[s4.z - r0], 1);
            if (s4.w >= r0 && s4.w < r1) atomicAdd(&ho[s4.w - r0], 1);
            if (d4.x >= r0 && d4.x < r1) atomicAdd(&hi[d4.x - r0], 1);
            if (d4.y >= r0 && d4.y < r1) atomicAdd(&hi[d4.y - r0], 1);
            if (d4.z >= r0 && d4.z < r1) atomicAdd(&hi[d4.z - r0], 1);
            if (d4.w >= r0 && d4.w < r1) atomicAdd(&hi[d4.w - r0], 1);
        } else {
            for (int j = 0; j < 4 && e + j < e1; ++j) {
                int s = src[e + j], d = dst[e + j];
                if (s >= r0 && s < r1) atomicAdd(&ho[s - r0], 1);
                if (d >= r0 && d < r1) atomicAdd(&hi[d - r0], 1);
            }
        }
    }
    __syncthreads();
    for (int i = threadIdx.x; i < nb; i += 256) {
        pout[(size_t)c * N + r0 + i] = ho[i];
        pin[(size_t)c * N + r0 + i] = hi[i];
    }
}

__global__ void k_reduce(const int* __restrict__ pout, const int* __restrict__ pin,
                         float* __restrict__ norm_out, float* __restrict__ norm_in,
                         int* __restrict__ deg_in, int N, int C) {
    int n = blockIdx.x * blockDim.x + threadIdx.x;
    if (n >= N) return;
    int so = 0, si = 0;
    for (int c = 0; c < C; ++c) {
        so += pout[(size_t)c * N + n];
        si += pin[(size_t)c * N + n];
    }
    norm_out[n] = rsqrtf(fmaxf((float)so, 1.0f));
    norm_in[n] = rsqrtf(fmaxf((float)si, 1.0f));
    deg_in[n] = si;
}

__global__ void k_base(const int* __restrict__ pin, const int* __restrict__ row_ptr,
                       int* __restrict__ base, int N, int C) {
    int n = blockIdx.x * blockDim.x + threadIdx.x;
    if (n >= N) return;
    int run = row_ptr[n];
    for (int c = 0; c < C; ++c) {
        int h = pin[(size_t)c * N + n];
        base[(size_t)c * N + n] = run;
        run += h;
    }
}

__global__ void k_gstart(const int* __restrict__ gid, int* g_start, int N, int G) {
    int g = blockIdx.x * blockDim.x + threadIdx.x;
    if (g > G) return;
    int lo = 0, hi = N;
    while (lo < hi) {
        int mid = (lo + hi) >> 1;
        if (gid[mid] < g) lo = mid + 1; else hi = mid;
    }
    g_start[g] = lo;
}

// ---------------- 3-phase scan ----------------
__global__ __launch_bounds__(256) void k_scan_a(const int* __restrict__ deg, int* bsum, int n) {
    __shared__ int wsum[4];
    int base = blockIdx.x * 1024 + threadIdx.x * 4;
    int s = 0;
    #pragma unroll
    for (int j = 0; j < 4; ++j) s += (base + j < n) ? deg[base + j] : 0;
    #pragma unroll
    for (int off = 32; off; off >>= 1) s += __shfl_xor(s, off);
    int lane = threadIdx.x & 63, w = threadIdx.x >> 6;
    if (lane == 0) wsum[w] = s;
    __syncthreads();
    if (threadIdx.x == 0) bsum[blockIdx.x] = wsum[0] + wsum[1] + wsum[2] + wsum[3];
}

__global__ void k_scan_b(int* bsum, int nblk, int* row_ptr, int n) {
    int lane = threadIdx.x;
    int carry = 0;
    for (int base = 0; base < nblk; base += 64) {
        int i = base + lane;
        int v = (i < nblk) ? bsum[i] : 0;
        int s = v;
        #pragma unroll
        for (int off = 1; off < 64; off <<= 1) {
            int u = __shfl_up(s, off);
            if (lane >= off) s += u;
        }
        if (i < nblk) bsum[i] = carry + s - v;
        carry += __shfl(s, 63);
    }
    if (lane == 0) row_ptr[n] = carry;
}

__global__ __launch_bounds__(256) void k_scan_c(const int* __restrict__ deg, const int* __restrict__ bsum,
                                                int* row_ptr, int n) {
    __shared__ int wsum[4];
    int t = threadIdx.x;
    int base = blockIdx.x * 1024 + t * 4;
    int v[4];
    #pragma unroll
    for (int j = 0; j < 4; ++j) v[j] = (base + j < n) ? deg[base + j] : 0;
    int ts = v[0] + v[1] + v[2] + v[3];
    int lane = t & 63, w = t >> 6;
    int incl = ts;
    #pragma unroll
    for (int off = 1; off < 64; off <<= 1) {
        int u = __shfl_up(incl, off);
        if (lane >= off) incl += u;
    }
    if (lane == 63) wsum[w] = incl;
    __syncthreads();
    int woff = 0;
    for (int j = 0; j < w; ++j) woff += wsum[j];
    int run = bsum[blockIdx.x] + woff + incl - ts;
    #pragma unroll
    for (int j = 0; j < 4; ++j) {
        if (base + j < n) row_ptr[base + j] = run;
        run += v[j];
    }
}

// fill CSR: LDS slot counters seeded from per-chunk base
__global__ __launch_bounds__(256) void k_fill2(const int* __restrict__ src, const int* __restrict__ dst,
                                               const int* __restrict__ base, int* __restrict__ col_src,
                                               int E, int N, int C, int RS, int L) {
    __shared__ int cnt[RSMAX];
    int r = blockIdx.x / C;
    int c = blockIdx.x % C;
    int r0 = r * RS;
    int r1 = min(r0 + RS, N);
    int nb = r1 - r0;
    const int* bc = base + (size_t)c * N;
    for (int i = threadIdx.x; i < nb; i += 256) cnt[i] = bc[r0 + i];
    __syncthreads();
    int e0 = c * L, e1 = min(e0 + L, E);
    for (int e = e0 + threadIdx.x * 4; e < e1; e += 1024) {
        if (e + 3 < e1) {
            int4 s4 = *(const int4*)&src[e];
            int4 d4 = *(const int4*)&dst[e];
            if (d4.x >= r0 && d4.x < r1) { int o = atomicAdd(&cnt[d4.x - r0], 1); col_src[o] = s4.x; }
            if (d4.y >= r0 && d4.y < r1) { int o = atomicAdd(&cnt[d4.y - r0], 1); col_src[o] = s4.y; }
            if (d4.z >= r0 && d4.z < r1) { int o = atomicAdd(&cnt[d4.z - r0], 1); col_src[o] = s4.z; }
            if (d4.w >= r0 && d4.w < r1) { int o = atomicAdd(&cnt[d4.w - r0], 1); col_src[o] = s4.w; }
        } else {
            for (int j = 0; j < 4 && e + j < e1; ++j) {
                int s = src[e + j], d = dst[e + j];
                if (d >= r0 && d < r1) { int o = atomicAdd(&cnt[d - r0], 1); col_src[o] = s; }
            }
        }
    }
}

// W[l] f32 [k][n] -> Wt half [n][k]
__global__ void k_wconv(const float* __restrict__ W, __half* __restrict__ Wt) {
    int i = blockIdx.x * blockDim.x + threadIdx.x;  // 3*16384
    if (i >= 3 * 16384) return;
    int l = i >> 14;
    int rem = i & 16383;
    int n = rem >> 7;
    int k = rem & 127;
    Wt[(size_t)l * 16384 + n * 128 + k] = __float2half(W[(size_t)l * 16384 + k * 128 + n]);
}

// pre-scale rows to half: Xh[n] = half(feats[n] * norm_out[n])
__global__ void k_scale(const float* __restrict__ h, const float* __restrict__ norm_out,
                        uint2* __restrict__ Xh, int N) {
    int i = blockIdx.x * blockDim.x + threadIdx.x;
    if (i < N * 32) {
        int n = i >> 5;
        float4 v = ((const float4*)h)[i];
        float s = norm_out[n];
        v.x *= s; v.y *= s; v.z *= s; v.w *= s;
        Xh[i] = pack_half4(v);
    }
}

__device__ inline void acc_row(float* acc, uint4 u) {
    const __half2* h = (const __half2*)&u;
    #pragma unroll
    for (int i = 0; i < 4; ++i) {
        float2 f = __half22float2(h[i]);
        acc[2 * i] += f.x;
        acc[2 * i + 1] += f.y;
    }
}

// pull-mode aggregation: 16 lanes/node, uint4 (8 halves) per lane, unroll x4 neighbors,
// f32 accumulate, half output. 16 nodes per 256-thread block, no LDS -> max occupancy.
__global__ __launch_bounds__(256, 8) void k_agg(const uint4* __restrict__ Xin, const float* __restrict__ norm_in,
                                                const int* __restrict__ row_ptr, const int* __restrict__ col_src,
                                                uint4* __restrict__ Yh, int N) {
    int t = threadIdx.x;
    int l16 = t & 15;             // uint4 lane within row
    int n = blockIdx.x * 16 + (t >> 4);
    if (n >= N) return;
    int beg = row_ptr[n], end = row_ptr[n + 1];
    float acc[8] = {};
    int k = beg;
    for (; k + 3 < end; k += 4) {
        int4 s = *(const int4*)&col_src[k];
        uint4 u0 = Xin[(size_t)s.x * 16 + l16];
        uint4 u1 = Xin[(size_t)s.y * 16 + l16];
        uint4 u2 = Xin[(size_t)s.z * 16 + l16];
        uint4 u3 = Xin[(size_t)s.w * 16 + l16];
        acc_row(acc, u0);
        acc_row(acc, u1);
        acc_row(acc, u2);
        acc_row(acc, u3);
    }
    for (; k < end; ++k) {
        uint4 u = Xin[(size_t)col_src[k] * 16 + l16];
        acc_row(acc, u);
    }
    float ni = norm_in[n];
    #pragma unroll
    for (int i = 0; i < 8; ++i) acc[i] *= ni;
    __half2 hp[4];
    #pragma unroll
    for (int i = 0; i < 4; ++i) hp[i] = __floats2half2_rn(acc[2 * i], acc[2 * i + 1]);
    Yh[(size_t)n * 16 + l16] = *(uint4*)hp;
}

// MFMA GEMM: z = relu(Yh[n] @ W + b); layers 0,1: outh = half(z * scale); layer 2: outf = z.
__global__ __launch_bounds__(256) void k_mm_mfma(const __half* __restrict__ Yh, const __half* __restrict__ Wt,
                                                 const float* __restrict__ bl, const float* __restrict__ scale,
                                                 float* __restrict__ outf, __half* __restrict__ outh, int N) {
    __shared__ _Float16 Ah[64 * 136];
    __shared__ _Float16 Bt[128 * 136];
    int tid = threadIdx.x;
    int n0 = blockIdx.x * 64;

    for (int q = tid; q < 1024; q += 256) {
        int r = q >> 4, c = q & 15;
        int node = n0 + r;
        float4 v = make_float4(0.f, 0.f, 0.f, 0.f);
        if (node < N) v = *(const float4*)&Yh[(size_t)node * 128 + c * 8];
        *(float4*)&Ah[r * 136 + c * 8] = v;
    }
    for (int q = tid; q < 2048; q += 256) {
        int r = q >> 4, c = q & 15;
        *(float4*)&Bt[r * 136 + c * 8] = *(const float4*)&Wt[(size_t)r * 128 + c * 8];
    }
    __syncthreads();

    int wave = tid >> 6;
    int lane = tid & 63;
    int quad = lane >> 4;
    int mrow = lane & 15;
    int m0 = wave * 16;

    half8 af[4];
    #pragma unroll
    for (int kc = 0; kc < 4; ++kc)
        af[kc] = *(const half8*)&Ah[(m0 + mrow) * 136 + kc * 32 + quad * 8];

    floatx4 acc[8];
    #pragma unroll
    for (int ct = 0; ct < 8; ++ct) acc[ct] = (floatx4){0.f, 0.f, 0.f, 0.f};

    #pragma unroll
    for (int ct = 0; ct < 8; ++ct) {
        #pragma unroll
        for (int kc = 0; kc < 4; ++kc) {
            half8 bf = *(const half8*)&Bt[(ct * 16 + mrow) * 136 + kc * 32 + quad * 8];
            acc[ct] = __builtin_amdgcn_mfma_f32_16x16x32_f16(af[kc], bf, acc[ct], 0, 0, 0);
        }
    }

    float sc[4];
    #pragma unroll
    for (int r = 0; r < 4; ++r) {
        int node = n0 + m0 + quad * 4 + r;
        sc[r] = (scale && node < N) ? scale[node] : 1.0f;
    }
    #pragma unroll
    for (int ct = 0; ct < 8; ++ct) {
        int col = ct * 16 + mrow;
        float bias = bl[col];
        #pragma unroll
        for (int r = 0; r < 4; ++r) {
            int node = n0 + m0 + quad * 4 + r;
            if (node < N) {
                float val = fmaxf(acc[ct][r] + bias, 0.f);
                if (outh) outh[(size_t)node * 128 + col] = __float2half(val * sc[r]);
                else outf[(size_t)node * 128 + col] = val;
            }
        }
    }
}

// pooled mean readout
__global__ __launch_bounds__(128) void k_pool(const float* __restrict__ h, const int* __restrict__ g_start,
                                              float* __restrict__ out) {
    int g = blockIdx.x;
    int t = threadIdx.x;
    int beg = g_start[g], end = g_start[g + 1];
    float acc = 0.0f;
    int n = beg;
    for (; n + 3 < end; n += 4) {
        float a0 = h[(size_t)n * DD + t];
        float a1 = h[(size_t)(n + 1) * DD + t];
        float a2 = h[(size_t)(n + 2) * DD + t];
        float a3 = h[(size_t)(n + 3) * DD + t];
        acc += a0 + a1 + a2 + a3;
    }
    for (; n < end; ++n) acc += h[(size_t)n * DD + t];
    float cnt = (float)(end - beg);
    out[(size_t)g * DD + t] = acc / fmaxf(cnt, 1.0f);
}

extern "C" void kernel_launch(void* const* d_in, const int* in_sizes, int n_in,
                              void* d_out, int out_size, void* d_ws, size_t ws_size,
                              hipStream_t stream) {
    const float* feats = (const float*)d_in[0];
    const float* W = (const float*)d_in[1];
    const float* b = (const float*)d_in[2];
    const int* src = (const int*)d_in[3];
    const int* dst = (const int*)d_in[4];
    const int* gid = (const int*)d_in[5];
    float* out = (float*)d_out;
    const int N = in_sizes[0] / DD;  // 50000
    const int E = in_sizes[3];       // 800000

    const int C = NCHUNK;
    const int RS = (N + RANGES - 1) / RANGES;
    const int L = (((E + C - 1) / C) + 3) & ~3;

    char* ws = (char*)d_ws;
    size_t off = 0;
    auto take = [&](size_t bytes) {
        char* p = ws + off;
        off = (off + bytes + 255) & ~(size_t)255;
        return p;
    };
    float* norm_out = (float*)take((size_t)N * 4);
    float* norm_in  = (float*)take((size_t)N * 4);
    int*   deg_in   = (int*)take((size_t)N * 4);
    int*   row_ptr  = (int*)take((size_t)(N + 1) * 4);
    int*   col_src  = (int*)take((size_t)E * 4);
    int*   g_start  = (int*)take((size_t)(GG + 1) * 4);
    int*   bsum     = (int*)take((size_t)1024 * 4);
    __half* Wth     = (__half*)take((size_t)3 * 16384 * 2);
    uint4* Xh       = (uint4*)take((size_t)N * DD * 2);   // half features
    uint4* Yh       = (uint4*)take((size_t)N * DD * 2);   // half agg output
    size_t part_bytes = 3 * ((size_t)C * N * 4 + 256);
    size_t f_bytes = (size_t)N * DD * 4;
    char* uni = take(part_bytes > f_bytes ? part_bytes : f_bytes);
    int* pout  = (int*)uni;
    int* pin   = (int*)(uni + (((size_t)C * N * 4 + 255) & ~(size_t)255));
    int* fbase = (int*)(uni + 2 * (((size_t)C * N * 4 + 255) & ~(size_t)255));
    float* F   = (float*)uni;  // alias: used only after preprocessing completes

    const int nblk = (N + 1023) / 1024;

    k_hist2<<<RANGES * C, 256, 0, stream>>>(src, dst, pout, pin, E, N, C, RS, L);
    k_reduce<<<(N + 255) / 256, 256, 0, stream>>>(pout, pin, norm_out, norm_in, deg_in, N, C);
    k_gstart<<<1, 512, 0, stream>>>(gid, g_start, N, GG);
    k_wconv<<<(3 * 16384 + 255) / 256, 256, 0, stream>>>(W, Wth);
    k_scan_a<<<nblk, 256, 0, stream>>>(deg_in, bsum, N);
    k_scan_b<<<1, 64, 0, stream>>>(bsum, nblk, row_ptr, N);
    k_scan_c<<<nblk, 256, 0, stream>>>(deg_in, bsum, row_ptr, N);
    k_base<<<(N + 255) / 256, 256, 0, stream>>>(pin, row_ptr, fbase, N, C);
    k_fill2<<<RANGES * C, 256, 0, stream>>>(src, dst, fbase, col_src, E, N, C, RS, L);

    k_scale<<<(N * 32 + 255) / 256, 256, 0, stream>>>(feats, norm_out, (uint2*)Xh, N);

    const int agrid = (N + 15) / 16;
    const int mgrid = (N + 63) / 64;
    for (int l = 0; l < 3; ++l) {
        k_agg<<<agrid, 256, 0, stream>>>(Xh, norm_in, row_ptr, col_src, Yh, N);
        const __half* Wtl = Wth + (size_t)l * 16384;
        const float* bl = b + (size_t)l * DD;
        if (l < 2)
            k_mm_mfma<<<mgrid, 256, 0, stream>>>((const __half*)Yh, Wtl, bl, norm_out,
                                                 nullptr, (__half*)Xh, N);
        else
            k_mm_mfma<<<mgrid, 256, 0, stream>>>((const __half*)Yh, Wtl, bl, nullptr,
                                                 F, nullptr, N);
    }
    k_pool<<<GG, 128, 0, stream>>>(F, g_start, out);
}

// Round 9
// 313.499 us; speedup vs baseline: 1.3172x; 1.0212x over previous
//
#include <hip/hip_runtime.h>
#include <hip/hip_fp16.h>

#define DD 128
#define GG 256
#define RANGES 8
#define RSMAX 6400
#define NCHUNK 32

typedef _Float16 half8 __attribute__((ext_vector_type(8)));
typedef float floatx4 __attribute__((ext_vector_type(4)));

__device__ inline uint2 pack_half4(float4 v) {
    __half2 a = __floats2half2_rn(v.x, v.y);
    __half2 b = __floats2half2_rn(v.z, v.w);
    uint2 u;
    u.x = *reinterpret_cast<unsigned int*>(&a);
    u.y = *reinterpret_cast<unsigned int*>(&b);
    return u;
}

// ---------------- LDS range-partitioned histogram, packed partials ----------------
// pk[c][n] = deg_out_partial | (deg_in_partial << 16)
__global__ __launch_bounds__(256) void k_hist2(const int* __restrict__ src, const int* __restrict__ dst,
                                               unsigned int* __restrict__ pk,
                                               int E, int N, int C, int RS, int L) {
    __shared__ int ho[RSMAX];
    __shared__ int hi[RSMAX];
    int r = blockIdx.x / C;
    int c = blockIdx.x % C;
    int r0 = r * RS;
    int r1 = min(r0 + RS, N);
    int nb = r1 - r0;
    for (int i = threadIdx.x; i < nb; i += 256) { ho[i] = 0; hi[i] = 0; }
    __syncthreads();
    int e0 = c * L, e1 = min(e0 + L, E);
    for (int e = e0 + threadIdx.x * 4; e < e1; e += 1024) {
        if (e + 3 < e1) {
            int4 s4 = *(const int4*)&src[e];
            int4 d4 = *(const int4*)&dst[e];
            if (s4.x >= r0 && s4.x < r1) atomicAdd(&ho[s4.x - r0], 1);
            if (s4.y >= r0 && s4.y < r1) atomicAdd(&ho[s4.y - r0], 1);
            if (s4.z >= r0 && s4.z < r1) atomicAdd(&ho[s4.z - r0], 1);
            if (s4.w >= r0 && s4.w < r1) atomicAdd(&ho[s4.w - r0], 1);
            if (d4.x >= r0 && d4.x < r1) atomicAdd(&hi[d4.x - r0], 1);
            if (d4.y >= r0 && d4.y < r1) atomicAdd(&hi[d4.y - r0], 1);
            if (d4.z >= r0 && d4.z < r1) atomicAdd(&hi[d4.z - r0], 1);
            if (d4.w >= r0 && d4.w < r1) atomicAdd(&hi[d4.w - r0], 1);
        } else {
            for (int j = 0; j < 4 && e + j < e1; ++j) {
                int s = src[e + j], d = dst[e + j];
                if (s >= r0 && s < r1) atomicAdd(&ho[s - r0], 1);
                if (d >= r0 && d < r1) atomicAdd(&hi[d - r0], 1);
            }
        }
    }
    __syncthreads();
    for (int i = threadIdx.x; i < nb; i += 256)
        pk[(size_t)c * N + r0 + i] = (unsigned int)ho[i] | ((unsigned int)hi[i] << 16);
}

__global__ void k_reduce(const unsigned int* __restrict__ pk,
                         float* __restrict__ norm_out, float* __restrict__ norm_in,
                         int* __restrict__ deg_in, int N, int C) {
    int n = blockIdx.x * blockDim.x + threadIdx.x;
    if (n >= N) return;
    int so = 0, si = 0;
    for (int c = 0; c < C; ++c) {
        unsigned int v = pk[(size_t)c * N + n];
        so += (int)(v & 0xFFFFu);
        si += (int)(v >> 16);
    }
    norm_out[n] = rsqrtf(fmaxf((float)so, 1.0f));
    norm_in[n] = rsqrtf(fmaxf((float)si, 1.0f));
    deg_in[n] = si;
}

__global__ void k_base(const unsigned int* __restrict__ pk, const int* __restrict__ row_ptr,
                       int* __restrict__ base, int N, int C) {
    int n = blockIdx.x * blockDim.x + threadIdx.x;
    if (n >= N) return;
    int run = row_ptr[n];
    for (int c = 0; c < C; ++c) {
        int h = (int)(pk[(size_t)c * N + n] >> 16);
        base[(size_t)c * N + n] = run;
        run += h;
    }
}

__global__ void k_gstart(const int* __restrict__ gid, int* g_start, int N, int G) {
    int g = blockIdx.x * blockDim.x + threadIdx.x;
    if (g > G) return;
    int lo = 0, hi = N;
    while (lo < hi) {
        int mid = (lo + hi) >> 1;
        if (gid[mid] < g) lo = mid + 1; else hi = mid;
    }
    g_start[g] = lo;
}

// ---------------- 3-phase scan ----------------
__global__ __launch_bounds__(256) void k_scan_a(const int* __restrict__ deg, int* bsum, int n) {
    __shared__ int wsum[4];
    int base = blockIdx.x * 1024 + threadIdx.x * 4;
    int s = 0;
    #pragma unroll
    for (int j = 0; j < 4; ++j) s += (base + j < n) ? deg[base + j] : 0;
    #pragma unroll
    for (int off = 32; off; off >>= 1) s += __shfl_xor(s, off);
    int lane = threadIdx.x & 63, w = threadIdx.x >> 6;
    if (lane == 0) wsum[w] = s;
    __syncthreads();
    if (threadIdx.x == 0) bsum[blockIdx.x] = wsum[0] + wsum[1] + wsum[2] + wsum[3];
}

__global__ void k_scan_b(int* bsum, int nblk, int* row_ptr, int n) {
    int lane = threadIdx.x;
    int carry = 0;
    for (int base = 0; base < nblk; base += 64) {
        int i = base + lane;
        int v = (i < nblk) ? bsum[i] : 0;
        int s = v;
        #pragma unroll
        for (int off = 1; off < 64; off <<= 1) {
            int u = __shfl_up(s, off);
            if (lane >= off) s += u;
        }
        if (i < nblk) bsum[i] = carry + s - v;
        carry += __shfl(s, 63);
    }
    if (lane == 0) row_ptr[n] = carry;
}

__global__ __launch_bounds__(256) void k_scan_c(const int* __restrict__ deg, const int* __restrict__ bsum,
                                                int* row_ptr, int n) {
    __shared__ int wsum[4];
    int t = threadIdx.x;
    int base = blockIdx.x * 1024 + t * 4;
    int v[4];
    #pragma unroll
    for (int j = 0; j < 4; ++j) v[j] = (base + j < n) ? deg[base + j] : 0;
    int ts = v[0] + v[1] + v[2] + v[3];
    int lane = t & 63, w = t >> 6;
    int incl = ts;
    #pragma unroll
    for (int off = 1; off < 64; off <<= 1) {
        int u = __shfl_up(incl, off);
        if (lane >= off) incl += u;
    }
    if (lane == 63) wsum[w] = incl;
    __syncthreads();
    int woff = 0;
    for (int j = 0; j < w; ++j) woff += wsum[j];
    int run = bsum[blockIdx.x] + woff + incl - ts;
    #pragma unroll
    for (int j = 0; j < 4; ++j) {
        if (base + j < n) row_ptr[base + j] = run;
        run += v[j];
    }
}

// fill CSR: LDS slot counters seeded from per-chunk base
__global__ __launch_bounds__(256) void k_fill2(const int* __restrict__ src, const int* __restrict__ dst,
                                               const int* __restrict__ base, int* __restrict__ col_src,
                                               int E, int N, int C, int RS, int L) {
    __shared__ int cnt[RSMAX];
    int r = blockIdx.x / C;
    int c = blockIdx.x % C;
    int r0 = r * RS;
    int r1 = min(r0 + RS, N);
    int nb = r1 - r0;
    const int* bc = base + (size_t)c * N;
    for (int i = threadIdx.x; i < nb; i += 256) cnt[i] = bc[r0 + i];
    __syncthreads();
    int e0 = c * L, e1 = min(e0 + L, E);
    for (int e = e0 + threadIdx.x * 4; e < e1; e += 1024) {
        if (e + 3 < e1) {
            int4 s4 = *(const int4*)&src[e];
            int4 d4 = *(const int4*)&dst[e];
            if (d4.x >= r0 && d4.x < r1) { int o = atomicAdd(&cnt[d4.x - r0], 1); col_src[o] = s4.x; }
            if (d4.y >= r0 && d4.y < r1) { int o = atomicAdd(&cnt[d4.y - r0], 1); col_src[o] = s4.y; }
            if (d4.z >= r0 && d4.z < r1) { int o = atomicAdd(&cnt[d4.z - r0], 1); col_src[o] = s4.z; }
            if (d4.w >= r0 && d4.w < r1) { int o = atomicAdd(&cnt[d4.w - r0], 1); col_src[o] = s4.w; }
        } else {
            for (int j = 0; j < 4 && e + j < e1; ++j) {
                int s = src[e + j], d = dst[e + j];
                if (d >= r0 && d < r1) { int o = atomicAdd(&cnt[d - r0], 1); col_src[o] = s; }
            }
        }
    }
}

// W[l] f32 [k][n] -> Wt half [n][k]
__global__ void k_wconv(const float* __restrict__ W, __half* __restrict__ Wt) {
    int i = blockIdx.x * blockDim.x + threadIdx.x;
    if (i >= 3 * 16384) return;
    int l = i >> 14;
    int rem = i & 16383;
    int n = rem >> 7;
    int k = rem & 127;
    Wt[(size_t)l * 16384 + n * 128 + k] = __float2half(W[(size_t)l * 16384 + k * 128 + n]);
}

// pre-scale rows to half
__global__ void k_scale(const float* __restrict__ h, const float* __restrict__ norm_out,
                        uint2* __restrict__ Xh, int N) {
    int i = blockIdx.x * blockDim.x + threadIdx.x;
    if (i < N * 32) {
        int n = i >> 5;
        float4 v = ((const float4*)h)[i];
        float s = norm_out[n];
        v.x *= s; v.y *= s; v.z *= s; v.w *= s;
        Xh[i] = pack_half4(v);
    }
}

__device__ inline void acc_row(float* acc, uint4 u) {
    const __half2* h = (const __half2*)&u;
    #pragma unroll
    for (int i = 0; i < 4; ++i) {
        float2 f = __half22float2(h[i]);
        acc[2 * i] += f.x;
        acc[2 * i + 1] += f.y;
    }
}

// pull-mode aggregation with index prefetch: 16 lanes/node, uint4 per lane.
__global__ __launch_bounds__(256, 8) void k_agg(const uint4* __restrict__ Xin, const float* __restrict__ norm_in,
                                                const int* __restrict__ row_ptr, const int* __restrict__ col_src,
                                                uint4* __restrict__ Yh, int N) {
    int t = threadIdx.x;
    int l16 = t & 15;
    int n = blockIdx.x * 16 + (t >> 4);
    if (n >= N) return;
    int beg = row_ptr[n], end = row_ptr[n + 1];
    float acc[8] = {};
    int k = beg;
    bool have = (k + 3 < end);
    int4 s;
    if (have) s = *(const int4*)&col_src[k];
    while (have) {
        int kn = k + 4;
        bool haven = (kn + 3 < end);
        int4 sn = s;
        if (haven) sn = *(const int4*)&col_src[kn];   // prefetch next indices
        uint4 u0 = Xin[(size_t)s.x * 16 + l16];
        uint4 u1 = Xin[(size_t)s.y * 16 + l16];
        uint4 u2 = Xin[(size_t)s.z * 16 + l16];
        uint4 u3 = Xin[(size_t)s.w * 16 + l16];
        acc_row(acc, u0);
        acc_row(acc, u1);
        acc_row(acc, u2);
        acc_row(acc, u3);
        s = sn; k = kn; have = haven;
    }
    for (; k < end; ++k) {
        uint4 u = Xin[(size_t)col_src[k] * 16 + l16];
        acc_row(acc, u);
    }
    float ni = norm_in[n];
    #pragma unroll
    for (int i = 0; i < 8; ++i) acc[i] *= ni;
    __half2 hp[4];
    #pragma unroll
    for (int i = 0; i < 4; ++i) hp[i] = __floats2half2_rn(acc[2 * i], acc[2 * i + 1]);
    Yh[(size_t)n * 16 + l16] = *(uint4*)hp;
}

// MFMA GEMM: z = relu(Yh[n] @ W + b); outh = half(z * sc) (sc=1 if scale null); or outf = z.
__global__ __launch_bounds__(256) void k_mm_mfma(const __half* __restrict__ Yh, const __half* __restrict__ Wt,
                                                 const float* __restrict__ bl, const float* __restrict__ scale,
                                                 float* __restrict__ outf, __half* __restrict__ outh, int N) {
    __shared__ _Float16 Ah[64 * 136];
    __shared__ _Float16 Bt[128 * 136];
    int tid = threadIdx.x;
    int n0 = blockIdx.x * 64;

    for (int q = tid; q < 1024; q += 256) {
        int r = q >> 4, c = q & 15;
        int node = n0 + r;
        float4 v = make_float4(0.f, 0.f, 0.f, 0.f);
        if (node < N) v = *(const float4*)&Yh[(size_t)node * 128 + c * 8];
        *(float4*)&Ah[r * 136 + c * 8] = v;
    }
    for (int q = tid; q < 2048; q += 256) {
        int r = q >> 4, c = q & 15;
        *(float4*)&Bt[r * 136 + c * 8] = *(const float4*)&Wt[(size_t)r * 128 + c * 8];
    }
    __syncthreads();

    int wave = tid >> 6;
    int lane = tid & 63;
    int quad = lane >> 4;
    int mrow = lane & 15;
    int m0 = wave * 16;

    half8 af[4];
    #pragma unroll
    for (int kc = 0; kc < 4; ++kc)
        af[kc] = *(const half8*)&Ah[(m0 + mrow) * 136 + kc * 32 + quad * 8];

    floatx4 acc[8];
    #pragma unroll
    for (int ct = 0; ct < 8; ++ct) acc[ct] = (floatx4){0.f, 0.f, 0.f, 0.f};

    #pragma unroll
    for (int ct = 0; ct < 8; ++ct) {
        #pragma unroll
        for (int kc = 0; kc < 4; ++kc) {
            half8 bf = *(const half8*)&Bt[(ct * 16 + mrow) * 136 + kc * 32 + quad * 8];
            acc[ct] = __builtin_amdgcn_mfma_f32_16x16x32_f16(af[kc], bf, acc[ct], 0, 0, 0);
        }
    }

    float sc[4];
    #pragma unroll
    for (int r = 0; r < 4; ++r) {
        int node = n0 + m0 + quad * 4 + r;
        sc[r] = (scale && node < N) ? scale[node] : 1.0f;
    }
    #pragma unroll
    for (int ct = 0; ct < 8; ++ct) {
        int col = ct * 16 + mrow;
        float bias = bl[col];
        #pragma unroll
        for (int r = 0; r < 4; ++r) {
            int node = n0 + m0 + quad * 4 + r;
            if (node < N) {
                float val = fmaxf(acc[ct][r] + bias, 0.f);
                if (outh) outh[(size_t)node * 128 + col] = __float2half(val * sc[r]);
                else outf[(size_t)node * 128 + col] = val;
            }
        }
    }
}

// pooled mean readout from half F: 4 nodes in flight, 64 col-pairs, LDS reduce.
__global__ __launch_bounds__(256) void k_pool(const __half2* __restrict__ Fh, const int* __restrict__ g_start,
                                              float* __restrict__ out) {
    __shared__ float2 red[4][64];
    int g = blockIdx.x;
    int t = threadIdx.x;
    int cp = t & 63;   // column pair
    int nl = t >> 6;   // 0..3
    int beg = g_start[g], end = g_start[g + 1];
    float2 acc = make_float2(0.f, 0.f);
    for (int n = beg + nl; n < end; n += 4) {
        float2 f = __half22float2(Fh[(size_t)n * 64 + cp]);
        acc.x += f.x;
        acc.y += f.y;
    }
    red[nl][cp] = acc;
    __syncthreads();
    if (nl == 0) {
        float2 a0 = red[0][cp], a1 = red[1][cp], a2 = red[2][cp], a3 = red[3][cp];
        float cnt = fmaxf((float)(end - beg), 1.0f);
        float2 o;
        o.x = (a0.x + a1.x + a2.x + a3.x) / cnt;
        o.y = (a0.y + a1.y + a2.y + a3.y) / cnt;
        *(float2*)&out[(size_t)g * DD + cp * 2] = o;
    }
}

extern "C" void kernel_launch(void* const* d_in, const int* in_sizes, int n_in,
                              void* d_out, int out_size, void* d_ws, size_t ws_size,
                              hipStream_t stream) {
    const float* feats = (const float*)d_in[0];
    const float* W = (const float*)d_in[1];
    const float* b = (const float*)d_in[2];
    const int* src = (const int*)d_in[3];
    const int* dst = (const int*)d_in[4];
    const int* gid = (const int*)d_in[5];
    float* out = (float*)d_out;
    const int N = in_sizes[0] / DD;  // 50000
    const int E = in_sizes[3];       // 800000

    const int C = NCHUNK;
    const int RS = (N + RANGES - 1) / RANGES;
    const int L = (((E + C - 1) / C) + 3) & ~3;

    char* ws = (char*)d_ws;
    size_t off = 0;
    auto take = [&](size_t bytes) {
        char* p = ws + off;
        off = (off + bytes + 255) & ~(size_t)255;
        return p;
    };
    float* norm_out = (float*)take((size_t)N * 4);
    float* norm_in  = (float*)take((size_t)N * 4);
    int*   deg_in   = (int*)take((size_t)N * 4);
    int*   row_ptr  = (int*)take((size_t)(N + 1) * 4);
    int*   col_src  = (int*)take((size_t)E * 4);
    int*   g_start  = (int*)take((size_t)(GG + 1) * 4);
    int*   bsum     = (int*)take((size_t)1024 * 4);
    __half* Wth     = (__half*)take((size_t)3 * 16384 * 2);
    uint4* Xh       = (uint4*)take((size_t)N * DD * 2);   // half features
    uint4* Yh       = (uint4*)take((size_t)N * DD * 2);   // half agg output
    // union: pk + fbase during preprocessing; Fh (half final layer) afterwards
    size_t chunk_arr = ((size_t)C * N * 4 + 255) & ~(size_t)255;
    size_t uni_bytes = 2 * chunk_arr;
    size_t fh_bytes = (size_t)N * DD * 2;
    char* uni = take(uni_bytes > fh_bytes ? uni_bytes : fh_bytes);
    unsigned int* pk = (unsigned int*)uni;
    int* fbase = (int*)(uni + chunk_arr);
    __half* Fh = (__half*)uni;  // alias: used only after preprocessing completes

    const int nblk = (N + 1023) / 1024;

    k_hist2<<<RANGES * C, 256, 0, stream>>>(src, dst, pk, E, N, C, RS, L);
    k_reduce<<<(N + 255) / 256, 256, 0, stream>>>(pk, norm_out, norm_in, deg_in, N, C);
    k_gstart<<<1, 512, 0, stream>>>(gid, g_start, N, GG);
    k_wconv<<<(3 * 16384 + 255) / 256, 256, 0, stream>>>(W, Wth);
    k_scan_a<<<nblk, 256, 0, stream>>>(deg_in, bsum, N);
    k_scan_b<<<1, 64, 0, stream>>>(bsum, nblk, row_ptr, N);
    k_scan_c<<<nblk, 256, 0, stream>>>(deg_in, bsum, row_ptr, N);
    k_base<<<(N + 255) / 256, 256, 0, stream>>>(pk, row_ptr, fbase, N, C);
    k_fill2<<<RANGES * C, 256, 0, stream>>>(src, dst, fbase, col_src, E, N, C, RS, L);

    k_scale<<<(N * 32 + 255) / 256, 256, 0, stream>>>(feats, norm_out, (uint2*)Xh, N);

    const int agrid = (N + 15) / 16;
    const int mgrid = (N + 63) / 64;
    for (int l = 0; l < 3; ++l) {
        k_agg<<<agrid, 256, 0, stream>>>(Xh, norm_in, row_ptr, col_src, Yh, N);
        const __half* Wtl = Wth + (size_t)l * 16384;
        const float* bl = b + (size_t)l * DD;
        if (l < 2)
            k_mm_mfma<<<mgrid, 256, 0, stream>>>((const __half*)Yh, Wtl, bl, norm_out,
                                                 nullptr, (__half*)Xh, N);
        else
            k_mm_mfma<<<mgrid, 256, 0, stream>>>((const __half*)Yh, Wtl, bl, nullptr,
                                                 nullptr, Fh, N);
    }
    k_pool<<<GG, 256, 0, stream>>>((const __half2*)Fh, g_start, out);
}